// Round 8
// baseline (1139.176 us; speedup 1.0000x reference)
//
#include <hip/hip_runtime.h>
#include <stdint.h>

#define B_ 4
#define N_ 256
#define H_ 192
#define H3_ 576
#define F_ 64
#define SH_ 24      // hidden rows / output slice per block (8 slices)
#define SC_ 72      // 3 gates * SH_ (slice cols for mv2)

// ---- workspace layout (32-bit words) ----
#define H0_OFF   0u
#define ZC_OFF   1024u
#define GHZ_OFF  2048u        // [b][576] z@W_hh + b_hh
#define SL2_OFF  8192u        // [b][t][192] S rows (plain f32)
#define HL2_OFF  204800u      // [b][t][192] h_prov rows (plain f32)
#define AN_OFF   401408u      // [b][t][4] u64 ancestor masks
#define TG_OFF   409600u      // [b][t][4] u64 target masks
#define PL_OFF   417792u      // parent lists (u8)
#define PC_OFF   483328u      // parent counts
#define DG_OFF   484352u      // 1/deg
#define CL_OFF   485376u      // children lists (u8)
#define CC_OFF   550912u      // children counts
#define PQ_OFF   551936u      // [slot2][b][k8][576] tagged u64 q-partials
#define G_OFF    625664u      // G^T: [b][k][N]
#define C_OFF    822272u      // C: [b][j][H]

#define AN64 (AN_OFF/2)
#define TG64 (TG_OFF/2)

#define NF_OUT 262144u
#define LL_OUT 327680u

__device__ __forceinline__ float sigm_(float x){ return 1.0f/(1.0f + __expf(-x)); }
__device__ __forceinline__ float tanh_(float x){
  float ax = fabsf(x);
  float e = __expf(-2.0f*ax);
  float t = (1.0f - e)/(1.0f + e);
  return x < 0.0f ? -t : t;
}

__device__ __forceinline__ void stq_(unsigned long long* p, float v, uint32_t tag){
  unsigned long long u = ((unsigned long long)tag<<32) | (unsigned long long)__float_as_uint(v);
  __hip_atomic_store(p, u, __ATOMIC_RELAXED, __HIP_MEMORY_SCOPE_AGENT);
}
// poll 8 q-partials for one column (k-stride = 576 u64); all 8 loads kept in flight
// per iteration. Returns the summed delta once all tags match.
__device__ __forceinline__ float poll8_(const unsigned long long* base, uint32_t tag){
  unsigned long long x[8];
  for(;;){
    #pragma unroll
    for (int k=0;k<8;k++)
      x[k] = __hip_atomic_load(base + (size_t)k*576, __ATOMIC_RELAXED, __HIP_MEMORY_SCOPE_AGENT);
    bool ok = true;
    #pragma unroll
    for (int k=0;k<8;k++) ok &= ((uint32_t)(x[k]>>32) == tag);
    if (__all((int)ok)) break;
  }
  float s = 0.f;
  #pragma unroll
  for (int k=0;k<8;k++) s += __uint_as_float((uint32_t)x[k]);
  return s;
}

// ---------- pre0: ghz[b][c] = z@W_hh + b_hh ----------
__global__ void __launch_bounds__(576) k_pre0(const float* __restrict__ z,
    const float* __restrict__ Whh, const float* __restrict__ bhh, float* ws)
{
  int b = blockIdx.x, tid = threadIdx.x;
  __shared__ float sz[H_];
  if (tid < H_) sz[tid] = z[b*H_ + tid];
  __syncthreads();
  float acc = 0.f;
  for (int k=0;k<H_;k++) acc += sz[k] * Whh[(size_t)k*H3_ + tid];
  ws[GHZ_OFF + b*H3_ + tid] = acc + bhh[tid];
}

// ---------- pre1: (bx<N_): parent lists/bitmasks/deg | (bx==N_): h0, zc, ll=0 ----------
__global__ void __launch_bounds__(192) k_pre1(const float* __restrict__ z,
    const float* __restrict__ Winit, const float* __restrict__ binit,
    const float* __restrict__ W1, const float* __restrict__ b1,
    const float* __restrict__ tgt, float* ws, float* out)
{
  int bx = blockIdx.x, b = blockIdx.y, tid = threadIdx.x;
  if (bx == N_){
    __shared__ float zs[H_];
    zs[tid] = z[b*H_ + tid];
    __syncthreads();
    float a0=0.f, a1=0.f;
    for (int k=0;k<H_;k++){
      float zv = zs[k];
      a0 += zv * Winit[(size_t)k*H_ + tid];
      a1 += zv * W1[(size_t)(2*H_ + k)*H_ + tid];
    }
    ws[H0_OFF + b*H_ + tid] = tanh_(a0 + binit[tid]);
    ws[ZC_OFF + b*H_ + tid] = a1 + b1[tid];
    if (b==0 && tid==0) out[LL_OUT] = 0.0f;
    return;
  }
  if (tid >= 64) return;
  int t = bx, lane = tid;
  uint32_t* wsu = (uint32_t*)ws;
  unsigned long long* ws64 = (unsigned long long*)ws;
  const float* row = tgt + ((size_t)(b*N_) + t)*N_;
  uint8_t* pl = ((uint8_t*)&wsu[PL_OFF]) + (size_t)(b*N_ + t)*N_;
  int cnt = 0;
  #pragma unroll
  for (int m=0;m<4;m++){
    float v = row[m*64 + lane];
    bool p = (v != 0.0f);
    unsigned long long bw = __ballot(p);
    if (lane == 0) ws64[TG64 + (size_t)(b*N_+t)*4 + m] = bw;
    if (p){
      int pos = cnt + (int)__popcll(bw & ((1ULL<<lane)-1ULL));
      pl[pos] = (uint8_t)(m*64 + lane);
    }
    cnt += (int)__popcll(bw);
  }
  if (lane == 0){
    wsu[PC_OFF + b*N_ + t] = (uint32_t)cnt;
    ws[DG_OFF + b*N_ + t] = 1.0f / fmaxf((float)cnt, 1.0f);
  }
}

// ---------- pre2: children lists (transpose of parent lists) ----------
__global__ void __launch_bounds__(64) k_pre2(float* ws)
{
  int j = blockIdx.x, b = blockIdx.y, lane = threadIdx.x;
  uint32_t* wsu = (uint32_t*)ws;
  unsigned long long* ws64 = (unsigned long long*)ws;
  uint8_t* cl = ((uint8_t*)&wsu[CL_OFF]) + (size_t)(b*N_ + j)*N_;
  int w = j >> 6; int sb = j & 63;
  int cnt = 0;
  #pragma unroll
  for (int m=0;m<4;m++){
    int t = m*64 + lane;
    unsigned long long rowm = ws64[TG64 + (size_t)(b*N_+t)*4 + w];
    bool p = ((rowm >> sb) & 1ULL) != 0ULL;
    unsigned long long bw = __ballot(p);
    if (p){
      int pos = cnt + (int)__popcll(bw & ((1ULL<<lane)-1ULL));
      cl[pos] = (uint8_t)t;
    }
    cnt += (int)__popcll(bw);
  }
  if (lane == 0) wsu[CC_OFF + b*N_ + j] = (uint32_t)cnt;
}

// ---------- pass 1: K-decomposed single-handshake recurrence ----------
// 576 threads, 8 blocks/batch. Block k holds W_ih[rows of slice k, all 576 cols]
// (24 regs/thread, col = tid) and W_hh[all rows, slice-k cols] (36 regs/thread).
// Per step: poll 8 q-partials/col (ONE handshake) -> full q -> full h_prov
// (redundant, in-block) -> mv2 (slice cols) -> h_new[slice] -> next q-partial
// publish. PQ double-buffered by step parity (producer leads <=1 step: safe).
__global__ void __launch_bounds__(576) k_pass1(const float* __restrict__ z,
    const float* __restrict__ Wih, const float* __restrict__ Whh,
    const float* __restrict__ bih_g, const float* __restrict__ bhh_g,
    float* ws)
{
  int bx = blockIdx.x;
  int b = bx & 7;
  if (b >= B_) return;
  int slice = bx >> 3;      // 0..7
  int tid = threadIdx.x;    // 0..575
  float* wsf = ws;
  uint32_t* wsu = (uint32_t*)ws;
  unsigned long long* ws64 = (unsigned long long*)ws;
  unsigned long long* PQ = (unsigned long long*)&wsu[PQ_OFF];

  __shared__ __align__(16) float sPS[N_*SC_];     // 73.7 KB: per-future-row msg partials (slice cols)
  __shared__ __align__(16) float sq[H3_];         // full q(t)
  __shared__ __align__(16) float sdelta[2][H3_];  // full q-delta ring
  __shared__ __align__(16) float shp[H_];         // full h_prov(t)
  __shared__ __align__(16) float sh_new[SH_];
  __shared__ __align__(16) float sghz[H3_], sbih[H3_], sbhh[H3_];
  __shared__ __align__(16) float sz[H_];
  __shared__ unsigned long long sAB[N_][4];
  __shared__ float sDG[N_], sTF1[N_], sTF2[N_];

  // ---- register weights ----
  float rwih[SH_];            // W_ih[slice rows][col tid]
  #pragma unroll
  for (int i=0;i<SH_;i++) rwih[i] = Wih[(size_t)(slice*SH_+i)*H3_ + tid];
  // mv2 mapping: threads tid<384: h = tid>>4 (0..23), kc = tid&15 (k-chunk of 12)
  const int h2 = tid >> 4, kc = tid & 15;
  const bool mv2 = (tid < 384);
  float rwhh[3][12];
  if (mv2){
    #pragma unroll
    for (int g=0; g<3; g++){
      int col = g*H_ + slice*SH_ + h2;
      #pragma unroll
      for (int i=0;i<12;i++) rwhh[g][i] = Whh[(size_t)(kc*12+i)*H3_ + col];
    }
  }

  // ---- LDS init ----
  sbih[tid] = bih_g[tid];
  sbhh[tid] = bhh_g[tid];
  sghz[tid] = wsf[GHZ_OFF + b*H3_ + tid];
  if (tid < H_) sz[tid] = z[b*H_ + tid];
  for (int i = tid; i < N_*SC_; i += 576) sPS[i] = 0.0f;
  if (tid < 4) sAB[0][tid] = 0ULL;
  for (int i = tid; i < N_; i += 576){
    sDG[i] = wsf[DG_OFF + b*N_ + i];
    float f1 = 0.f, f2 = 0.f;
    if (i >= 1){
      unsigned long long w1 = ws64[TG64 + (size_t)(b*N_+i)*4 + ((i-1)>>6)];
      f1 = (float)((w1 >> ((i-1)&63)) & 1ULL);
    }
    if (i >= 2){
      unsigned long long w2 = ws64[TG64 + (size_t)(b*N_+i)*4 + ((i-2)>>6)];
      f2 = (float)((w2 >> ((i-2)&63)) & 1ULL);
    }
    sTF1[i] = f1; sTF2[i] = f2;
  }
  // S(0)=h0: export slice to SL2, publish startup q-partial (slot 1, tag 1)
  float h0s[SH_];
  #pragma unroll
  for (int i=0;i<SH_;i++) h0s[i] = wsf[H0_OFF + b*H_ + slice*SH_ + i];
  if (tid >= slice*SH_ && tid < slice*SH_+SH_)
    wsf[SL2_OFF + (unsigned)(b*N_)*192u + tid] = h0s[tid - slice*SH_];
  {
    float pc = 0.f;
    #pragma unroll
    for (int i=0;i<SH_;i++) pc += h0s[i]*rwih[i];
    stq_(&PQ[((size_t)(1*4 + b)*8 + slice)*576 + tid], pc, 1u);
  }
  __syncthreads();

  float qc = 0.f;   // running q for column tid

  for (int t=1; t<N_; t++){
    const uint32_t tag = (uint32_t)t;
    // ---- phase A: ONE handshake — poll 8 partials for col tid, fold ----
    {
      float d = poll8_(&PQ[((size_t)((t&1)*4 + b)*8 + 0)*576 + tid], tag);
      qc += d;
      sq[tid] = qc;
      sdelta[t&1][tid] = d;
    }
    __syncthreads();   // B1
    // ---- phase B: full h_prov (tid<192) | scatter (384..455) | ancestor (456..459) ----
    if (tid < H_){
      float invt = 1.0f/(float)t;
      float a10 = sq[tid]*invt       + sbih[tid];
      float a11 = sq[H_+tid]*invt    + sbih[H_+tid];
      float a12 = sq[2*H_+tid]*invt  + sbih[2*H_+tid];
      float r = sigm_(a10 + sghz[tid]);
      float u = sigm_(a11 + sghz[H_+tid]);
      float n = tanh_(a12 + r*sghz[2*H_+tid]);
      float hp = (1.0f-u)*n + u*sz[tid];
      shp[tid] = hp;
      if (tid >= slice*SH_ && tid < slice*SH_+SH_)
        wsf[HL2_OFF + (unsigned)(b*N_+t)*192u + tid] = hp;
    } else if (tid >= 384 && tid < 384+SC_){
      // delayed scatter: node t-2's delta -> children rows > t (slice cols)
      if (t >= 2){
        int cc = tid - 384;
        int g = cc/SH_, hcol = cc%SH_;
        int gcol = g*H_ + slice*SH_ + hcol;
        int node = t-2;
        int ccn = (int)wsu[CC_OFF + b*N_ + node];
        const uint8_t* cl = ((const uint8_t*)&wsu[CL_OFF]) + (size_t)(b*N_ + node)*N_;
        float dd = sdelta[(t-1)&1][gcol];
        for (int i=0;i<ccn;i++){
          int tc = cl[i];
          if (tc > t) sPS[tc*SC_ + cc] += dd;
        }
      }
    } else if (tid >= 456 && tid < 460){
      int w = tid - 456;
      int npt = (int)wsu[PC_OFF + b*N_ + t];
      const uint8_t* pb = ((const uint8_t*)&wsu[PL_OFF]) + (size_t)(b*N_ + t)*N_;
      unsigned long long acc = 0ULL;
      for (int i=0;i<npt;i++) acc |= sAB[pb[i]][w];
      if (slice == 0) ws64[AN64 + (size_t)(b*N_+t)*4 + w] = acc;
      sAB[t][w] = acc | ws64[TG64 + (size_t)(b*N_+t)*4 + w];
    }
    __syncthreads();   // B2
    // ---- phase CD: mv2 + gates2 (tid<384; gh2 full in all 16 kc lanes) ----
    if (mv2){
      float x[12];
      #pragma unroll
      for (int i=0;i<12;i++) x[i] = shp[kc*12 + i];
      float y0=0.f,y1=0.f,y2=0.f;
      #pragma unroll
      for (int i=0;i<12;i++){
        y0 += x[i]*rwhh[0][i]; y1 += x[i]*rwhh[1][i]; y2 += x[i]*rwhh[2][i];
      }
      #pragma unroll
      for (int m=1;m<16;m<<=1){
        y0 += __shfl_xor(y0,m); y1 += __shfl_xor(y1,m); y2 += __shfl_xor(y2,m);
      }
      float dginv = sDG[t], tf1 = sTF1[t], tf2 = sTF2[t];
      int c0g = 0*H_ + slice*SH_ + h2;
      int c1g = 1*H_ + slice*SH_ + h2;
      int c2g = 2*H_ + slice*SH_ + h2;
      float a20 = (sPS[t*SC_ + 0*SH_ + h2] + tf1*sdelta[t&1][c0g] + tf2*sdelta[(t-1)&1][c0g])*dginv + sbih[c0g];
      float a21 = (sPS[t*SC_ + 1*SH_ + h2] + tf1*sdelta[t&1][c1g] + tf2*sdelta[(t-1)&1][c1g])*dginv + sbih[c1g];
      float a22 = (sPS[t*SC_ + 2*SH_ + h2] + tf1*sdelta[t&1][c2g] + tf2*sdelta[(t-1)&1][c2g])*dginv + sbih[c2g];
      float r2 = sigm_(a20 + y0 + sbhh[c0g]);
      float u2 = sigm_(a21 + y1 + sbhh[c1g]);
      float n2 = tanh_(a22 + r2*(y2 + sbhh[c2g]));
      float hn = (1.0f-u2)*n2 + u2*shp[slice*SH_ + h2];
      if (kc == 0){
        sh_new[h2] = hn;
        wsf[SL2_OFF + (unsigned)(b*N_+t)*192u + slice*SH_ + h2] = hn;
      }
    }
    __syncthreads();   // B3
    // ---- phase E: next q-partial publish (all 576) ----
    {
      float pc = 0.f;
      #pragma unroll
      for (int i=0;i<SH_;i++) pc += sh_new[i]*rwih[i];
      stq_(&PQ[((size_t)(((t+1)&1)*4 + b)*8 + slice)*576 + tid], pc, (uint32_t)(t+1));
    }
    __syncthreads();   // B4 (protect sq/sdelta/sh_new before next A/B)
  }
}

// ---------- pass 2a: tiled (8 rows/block): G^T, C, NF ----------
__global__ void __launch_bounds__(192) k_p2a(const float* __restrict__ W1,
    const float* __restrict__ Wf, const float* __restrict__ bf, float* ws, float* out)
{
  int j0 = blockIdx.x * 8, b = blockIdx.y, tid = threadIdx.x;
  __shared__ float srow[8][H_], hrow[8][H_];
  __shared__ float nfp[3][8][F_];
  for (int r=0;r<8;r++){
    srow[r][tid] = ws[SL2_OFF + (unsigned)(b*N_+j0+r)*192u + tid];
    hrow[r][tid] = ws[HL2_OFF + (unsigned)(b*N_+j0+r)*192u + tid];  // row0 garbage, C[0] unused
  }
  __syncthreads();
  float accG[8], accC[8];
  #pragma unroll
  for (int r=0;r<8;r++){ accG[r]=0.f; accC[r]=0.f; }
  for (int k=0;k<H_;k++){
    float w1a = W1[(size_t)k*H_ + tid];
    float w1b = W1[(size_t)(H_+k)*H_ + tid];
    #pragma unroll
    for (int r=0;r<8;r++){
      accG[r] += srow[r][k]*w1b;
      accC[r] += hrow[r][k]*w1a;
    }
  }
  float zc = ws[ZC_OFF + b*H_ + tid];
  #pragma unroll
  for (int r=0;r<8;r++){
    ws[G_OFF + ((size_t)b*H_ + tid)*N_ + j0 + r] = accG[r];
    ws[C_OFF + (size_t)(b*N_+j0+r)*H_ + tid] = accC[r] + zc;
  }
  // NF = S@Wf + bf
  int f = tid & 63, kp = tid >> 6;
  float acc[8];
  #pragma unroll
  for (int r=0;r<8;r++) acc[r] = 0.f;
  for (int i=0;i<64;i++){
    int k = kp*64 + i;
    float wfv = Wf[(size_t)k*F_ + f];
    #pragma unroll
    for (int r=0;r<8;r++) acc[r] += srow[r][k]*wfv;
  }
  #pragma unroll
  for (int r=0;r<8;r++) nfp[kp][r][f] = acc[r];
  __syncthreads();
  if (tid < F_){
    #pragma unroll
    for (int r=0;r<8;r++)
      out[NF_OUT + (size_t)(b*N_+j0+r)*F_ + tid] = nfp[0][r][tid]+nfp[1][r][tid]+nfp[2][r][tid] + bf[tid];
  }
}

// ---------- pass 2b: log-likelihood, lane-per-candidate-parent ----------
__global__ void __launch_bounds__(256) k_p2b(const float* __restrict__ W2,
    const float* __restrict__ b2p, float* ws, float* out)
{
  int t = blockIdx.x + 1, b = blockIdx.y;
  int tid = threadIdx.x; int lane = tid & 63; int wv = tid >> 6;
  __shared__ float cv[H_], w2s[H_];
  __shared__ float wsum[4];
  unsigned long long* ws64 = (unsigned long long*)ws;
  if (tid < H_){
    cv[tid] = ws[C_OFF + (size_t)(b*N_+t)*H_ + tid];
    w2s[tid] = W2[tid];
  }
  __syncthreads();
  float acc = 0.f;
  if (tid < t){
    const float* GT = ws + G_OFF + (size_t)b*H_*N_;
    float a = 0.f;
    for (int k=0;k<H_;k++) a += fmaxf(cv[k] + GT[(size_t)k*N_ + tid], 0.f) * w2s[k];
    float logit = a + b2p[0];
    float pp = 1.0f/(1.0f+__expf(-logit));
    unsigned long long an = ws64[AN64 + (size_t)(b*N_+t)*4 + (tid>>6)];
    unsigned long long tg = ws64[TG64 + (size_t)(b*N_+t)*4 + (tid>>6)];
    float anc = (float)((an >> (tid&63)) & 1ULL);
    pp = pp * (1.0f - anc);
    pp = fminf(fmaxf(pp, 1e-6f), 1.0f - 1e-6f);
    int tgb = (int)((tg >> (tid&63)) & 1ULL);
    acc = tgb ? logf(pp) : log1pf(-pp);
  }
  #pragma unroll
  for (int m=32;m>=1;m>>=1) acc += __shfl_xor(acc, m);
  if (lane == 0) wsum[wv] = acc;
  __syncthreads();
  if (tid == 0) atomicAdd(out + LL_OUT, wsum[0]+wsum[1]+wsum[2]+wsum[3]);
}

extern "C" void kernel_launch(void* const* d_in, const int* in_sizes, int n_in,
                              void* d_out, int out_size, void* d_ws, size_t ws_size,
                              hipStream_t stream) {
  (void)in_sizes; (void)n_in; (void)out_size; (void)ws_size;
  const float* z     = (const float*)d_in[0];
  const float* tgt   = (const float*)d_in[1];
  const float* Winit = (const float*)d_in[2];
  const float* binit = (const float*)d_in[3];
  const float* Wih   = (const float*)d_in[4];
  const float* Whh   = (const float*)d_in[5];
  const float* bih   = (const float*)d_in[6];
  const float* bhh   = (const float*)d_in[7];
  const float* W1    = (const float*)d_in[8];
  const float* b1    = (const float*)d_in[9];
  const float* W2    = (const float*)d_in[10];
  const float* b2    = (const float*)d_in[11];
  const float* Wf    = (const float*)d_in[12];
  const float* bf    = (const float*)d_in[13];
  float* out = (float*)d_out;
  float* ws  = (float*)d_ws;

  hipMemcpyAsync(d_out, d_in[1], (size_t)B_*N_*N_*sizeof(float), hipMemcpyDeviceToDevice, stream);

  k_pre0<<<dim3(B_), dim3(H3_), 0, stream>>>(z, Whh, bhh, ws);
  k_pre1<<<dim3(N_+1, B_), dim3(192), 0, stream>>>(z, Winit, binit, W1, b1, tgt, ws, out);
  k_pre2<<<dim3(N_, B_), dim3(64), 0, stream>>>(ws);
  k_pass1<<<dim3(64), dim3(H3_), 0, stream>>>(z, Wih, Whh, bih, bhh, ws);
  k_p2a<<<dim3(N_/8, B_), dim3(192), 0, stream>>>(W1, Wf, bf, ws, out);
  k_p2b<<<dim3(N_-1, B_), dim3(256), 0, stream>>>(W2, b2, ws, out);
}

// Round 10
// 1129.163 us; speedup vs baseline: 1.0089x; 1.0089x over previous
//
#include <hip/hip_runtime.h>
#include <stdint.h>

#define B_ 4
#define N_ 256
#define H_ 192
#define H3_ 576
#define F_ 64
#define SH_ 24      // hidden rows / output slice per block (8 slices)
#define SC_ 72      // 3 gates * SH_ (slice cols for mv2)

// ---- workspace layout (32-bit words) ----
#define H0_OFF   0u
#define ZC_OFF   1024u
#define GHZ_OFF  2048u        // [b][576] z@W_hh + b_hh
#define SL2_OFF  8192u        // [b][t][192] S rows (plain f32)
#define HL2_OFF  204800u      // [b][t][192] h_prov rows (plain f32)
#define AN_OFF   401408u      // [b][t][4] u64 ancestor masks
#define TG_OFF   409600u      // [b][t][4] u64 target masks
#define PL_OFF   417792u      // parent lists (u8)
#define PC_OFF   483328u      // parent counts
#define DG_OFF   484352u      // 1/deg
#define CL_OFF   485376u      // children lists (u8)
#define CC_OFF   550912u      // children counts
#define D_OFF    551936u      // [par2][b][576] u64 fixed-point delta accumulators
#define G_OFF    625664u      // G^T: [b][k][N]
#define C_OFF    822272u      // C: [b][j][H]

#define AN64 (AN_OFF/2)
#define TG64 (TG_OFF/2)
#define D64  (D_OFF/2)

#define NF_OUT 262144u
#define LL_OUT 327680u

#define FPSCALE 16777216.0f          // 2^24
#define FPINV   5.9604644775390625e-8f

__device__ __forceinline__ float sigm_(float x){ return 1.0f/(1.0f + __expf(-x)); }
__device__ __forceinline__ float tanh_(float x){
  float ax = fabsf(x);
  float e = __expf(-2.0f*ax);
  float t = (1.0f - e)/(1.0f + e);
  return x < 0.0f ? -t : t;
}

// encode partial delta as (fix24 << 12) | 1 : low 12 bits = arrival count.
// Counts: 8 blocks x <=128 uses/slot = <=1024 < 4096, never carries into value.
__device__ __forceinline__ unsigned long long encd_(float v){
  long long f = (long long)llrintf(v * FPSCALE);
  return (((unsigned long long)f) << 12) | 1ull;
}

// ---------- pre0: ghz[b][c] = z@W_hh + b_hh ----------
__global__ void __launch_bounds__(576) k_pre0(const float* __restrict__ z,
    const float* __restrict__ Whh, const float* __restrict__ bhh, float* ws)
{
  int b = blockIdx.x, tid = threadIdx.x;
  __shared__ float sz[H_];
  if (tid < H_) sz[tid] = z[b*H_ + tid];
  __syncthreads();
  float acc = 0.f;
  for (int k=0;k<H_;k++) acc += sz[k] * Whh[(size_t)k*H3_ + tid];
  ws[GHZ_OFF + b*H3_ + tid] = acc + bhh[tid];
}

// ---------- pre1: (bx<N_): parent lists/bitmasks/deg | (bx==N_): h0, zc, ll=0, zero D ----------
__global__ void __launch_bounds__(192) k_pre1(const float* __restrict__ z,
    const float* __restrict__ Winit, const float* __restrict__ binit,
    const float* __restrict__ W1, const float* __restrict__ b1,
    const float* __restrict__ tgt, float* ws, float* out)
{
  int bx = blockIdx.x, b = blockIdx.y, tid = threadIdx.x;
  unsigned long long* ws64 = (unsigned long long*)ws;
  if (bx == N_){
    for (int i = tid; i < 2*H3_; i += 192){
      int par = i / H3_, col = i % H3_;
      ws64[D64 + ((size_t)(par*4 + b))*H3_ + col] = 0ULL;
    }
    __shared__ float zs[H_];
    zs[tid] = z[b*H_ + tid];
    __syncthreads();
    float a0=0.f, a1=0.f;
    for (int k=0;k<H_;k++){
      float zv = zs[k];
      a0 += zv * Winit[(size_t)k*H_ + tid];
      a1 += zv * W1[(size_t)(2*H_ + k)*H_ + tid];
    }
    ws[H0_OFF + b*H_ + tid] = tanh_(a0 + binit[tid]);
    ws[ZC_OFF + b*H_ + tid] = a1 + b1[tid];
    if (b==0 && tid==0) out[LL_OUT] = 0.0f;
    return;
  }
  if (tid >= 64) return;
  int t = bx, lane = tid;
  uint32_t* wsu = (uint32_t*)ws;
  const float* row = tgt + ((size_t)(b*N_) + t)*N_;
  uint8_t* pl = ((uint8_t*)&wsu[PL_OFF]) + (size_t)(b*N_ + t)*N_;
  int cnt = 0;
  #pragma unroll
  for (int m=0;m<4;m++){
    float v = row[m*64 + lane];
    bool p = (v != 0.0f);
    unsigned long long bw = __ballot(p);
    if (lane == 0) ws64[TG64 + (size_t)(b*N_+t)*4 + m] = bw;
    if (p){
      int pos = cnt + (int)__popcll(bw & ((1ULL<<lane)-1ULL));
      pl[pos] = (uint8_t)(m*64 + lane);
    }
    cnt += (int)__popcll(bw);
  }
  if (lane == 0){
    wsu[PC_OFF + b*N_ + t] = (uint32_t)cnt;
    ws[DG_OFF + b*N_ + t] = 1.0f / fmaxf((float)cnt, 1.0f);
  }
}

// ---------- pre2: children lists (transpose of parent lists) ----------
__global__ void __launch_bounds__(64) k_pre2(float* ws)
{
  int j = blockIdx.x, b = blockIdx.y, lane = threadIdx.x;
  uint32_t* wsu = (uint32_t*)ws;
  unsigned long long* ws64 = (unsigned long long*)ws;
  uint8_t* cl = ((uint8_t*)&wsu[CL_OFF]) + (size_t)(b*N_ + j)*N_;
  int w = j >> 6; int sb = j & 63;
  int cnt = 0;
  #pragma unroll
  for (int m=0;m<4;m++){
    int t = m*64 + lane;
    unsigned long long rowm = ws64[TG64 + (size_t)(b*N_+t)*4 + w];
    bool p = ((rowm >> sb) & 1ULL) != 0ULL;
    unsigned long long bw = __ballot(p);
    if (p){
      int pos = cnt + (int)__popcll(bw & ((1ULL<<lane)-1ULL));
      cl[pos] = (uint8_t)t;
    }
    cnt += (int)__popcll(bw);
  }
  if (lane == 0) wsu[CC_OFF + b*N_ + j] = (uint32_t)cnt;
}

// ---------- pass 1: single-leg fixed-point accumulator exchange ----------
// 576 threads, 8 blocks/batch. Per step: each thread polls ITS u64 accumulator word
// until arrival-count==8k (value rides along, integer-exact decode) -> full q ->
// full h_prov (redundant per block) -> mv2 (register W_hh slice) -> h_new[slice] ->
// ONE u64 atomic add per thread publishes the next q-delta partial. No drains/tags.
// Safety: poll(t+1) success requires all blocks' publish(t), which requires all
// blocks' poll(t) — a consumer can never miss its count window.
__global__ void __launch_bounds__(576) k_pass1(const float* __restrict__ z,
    const float* __restrict__ Wih, const float* __restrict__ Whh,
    const float* __restrict__ bih_g, const float* __restrict__ bhh_g,
    float* ws)
{
  int bx = blockIdx.x;
  int b = bx & 7;
  if (b >= B_) return;
  int slice = bx >> 3;      // 0..7
  int tid = threadIdx.x;    // 0..575
  float* wsf = ws;
  uint32_t* wsu = (uint32_t*)ws;
  unsigned long long* ws64 = (unsigned long long*)ws;

  __shared__ __align__(16) float sPS[N_*SC_];
  __shared__ __align__(16) float sq[H3_];
  __shared__ __align__(16) float sdq[2][H3_];
  __shared__ __align__(16) float shp[H_];
  __shared__ __align__(16) float sh_new[SH_];
  __shared__ __align__(16) float sghz[H3_], sbih[H3_], sbhh[H3_];
  __shared__ __align__(16) float sz[H_];
  __shared__ unsigned long long sAB[N_][4];
  __shared__ float sDG[N_], sTF1[N_], sTF2[N_];

  // ---- register weights ----
  float rwih[SH_];            // W_ih[slice rows][col tid]
  #pragma unroll
  for (int i=0;i<SH_;i++) rwih[i] = Wih[(size_t)(slice*SH_+i)*H3_ + tid];
  const int h2 = tid >> 4, kc = tid & 15;
  const bool mv2 = (tid < 384);
  float rwhh[3][12];
  if (mv2){
    #pragma unroll
    for (int g=0; g<3; g++){
      int col = g*H_ + slice*SH_ + h2;
      #pragma unroll
      for (int i=0;i<12;i++) rwhh[g][i] = Whh[(size_t)(kc*12+i)*H3_ + col];
    }
  }

  // ---- LDS init (NOTE: sdq zero-init is mandatory — t=1 reads sdq[0] with tf2=0,
  // and 0*NaN-patterned leftover LDS poisons the recurrence; bit us in r9) ----
  sbih[tid] = bih_g[tid];
  sbhh[tid] = bhh_g[tid];
  sghz[tid] = wsf[GHZ_OFF + b*H3_ + tid];
  sdq[0][tid] = 0.0f;
  sdq[1][tid] = 0.0f;
  if (tid < H_) sz[tid] = z[b*H_ + tid];
  for (int i = tid; i < N_*SC_; i += 576) sPS[i] = 0.0f;
  if (tid < 4) sAB[0][tid] = 0ULL;
  for (int i = tid; i < N_; i += 576){
    sDG[i] = wsf[DG_OFF + b*N_ + i];
    float f1 = 0.f, f2 = 0.f;
    if (i >= 1){
      unsigned long long w1 = ws64[TG64 + (size_t)(b*N_+i)*4 + ((i-1)>>6)];
      f1 = (float)((w1 >> ((i-1)&63)) & 1ULL);
    }
    if (i >= 2){
      unsigned long long w2 = ws64[TG64 + (size_t)(b*N_+i)*4 + ((i-2)>>6)];
      f2 = (float)((w2 >> ((i-2)&63)) & 1ULL);
    }
    sTF1[i] = f1; sTF2[i] = f2;
  }
  // S(0)=h0: export slice, publish startup delta(1) into D[1]
  {
    float h0s[SH_];
    #pragma unroll
    for (int i=0;i<SH_;i++) h0s[i] = wsf[H0_OFF + b*H_ + slice*SH_ + i];
    if (tid >= slice*SH_ && tid < slice*SH_+SH_)
      wsf[SL2_OFF + (unsigned)(b*N_)*192u + tid] = h0s[tid - slice*SH_];
    float pc = 0.f;
    #pragma unroll
    for (int i=0;i<SH_;i++) pc += h0s[i]*rwih[i];
    __hip_atomic_fetch_add(&ws64[D64 + ((size_t)(1*4 + b))*H3_ + tid], encd_(pc),
                           __ATOMIC_RELAXED, __HIP_MEMORY_SCOPE_AGENT);
  }
  __syncthreads();

  long long prevI[2] = {0ll, 0ll};     // integer-exact accumulated value per slot
  uint32_t expcnt[2] = {8u, 8u};
  unsigned long long* Dp[2] = {
    &ws64[D64 + ((size_t)(0*4 + b))*H3_ + tid],
    &ws64[D64 + ((size_t)(1*4 + b))*H3_ + tid]
  };

  for (int t=1; t<N_; t++){
    const int par = t & 1;
    // ---- phase A: poll own accumulator word (1 load/lane/iter; no vote — B1 syncs) ----
    {
      unsigned long long w;
      const uint32_t ec = expcnt[par];
      do {
        w = __hip_atomic_load(Dp[par], __ATOMIC_RELAXED, __HIP_MEMORY_SCOPE_AGENT);
      } while ((uint32_t)(w & 0xFFFull) != ec);
      expcnt[par] = ec + 8u;
      long long sv = ((long long)w) >> 12;              // exact Σf (sign from bit 63)
      float d = (float)(sv - prevI[par]) * FPINV;       // exact integer diff -> f32
      prevI[par] = sv;
      sq[tid] = (float)(prevI[0] + prevI[1]) * FPINV;   // exact fixed-point q
      sdq[par][tid] = d;
    }
    __syncthreads();   // B1
    // ---- phase B: full h_prov (tid<192) | PS scatter (384..455) | ancestor (456..459) ----
    if (tid < H_){
      float invt = 1.0f/(float)t;
      float a10 = sq[tid]*invt       + sbih[tid];
      float a11 = sq[H_+tid]*invt    + sbih[H_+tid];
      float a12 = sq[2*H_+tid]*invt  + sbih[2*H_+tid];
      float r = sigm_(a10 + sghz[tid]);
      float u = sigm_(a11 + sghz[H_+tid]);
      float n = tanh_(a12 + r*sghz[2*H_+tid]);
      float hp = (1.0f-u)*n + u*sz[tid];
      shp[tid] = hp;
      if (tid >= slice*SH_ && tid < slice*SH_+SH_)
        wsf[HL2_OFF + (unsigned)(b*N_+t)*192u + tid] = hp;
    } else if (tid >= 384 && tid < 384+SC_){
      if (t >= 2){
        int cc = tid - 384;
        int g = cc/SH_, hcol = cc%SH_;
        int gcol = g*H_ + slice*SH_ + hcol;
        int node = t-2;
        int ccn = (int)wsu[CC_OFF + b*N_ + node];
        const uint8_t* cl = ((const uint8_t*)&wsu[CL_OFF]) + (size_t)(b*N_ + node)*N_;
        float dd = sdq[(t-1)&1][gcol];
        for (int i=0;i<ccn;i++){
          int tc = cl[i];
          if (tc > t) sPS[tc*SC_ + cc] += dd;
        }
      }
    } else if (tid >= 456 && tid < 460){
      int w = tid - 456;
      int npt = (int)wsu[PC_OFF + b*N_ + t];
      const uint8_t* pb = ((const uint8_t*)&wsu[PL_OFF]) + (size_t)(b*N_ + t)*N_;
      unsigned long long acc = 0ULL;
      for (int i=0;i<npt;i++) acc |= sAB[pb[i]][w];
      if (slice == 0) ws64[AN64 + (size_t)(b*N_+t)*4 + w] = acc;
      sAB[t][w] = acc | ws64[TG64 + (size_t)(b*N_+t)*4 + w];
    }
    __syncthreads();   // B2
    // ---- phase C: mv2 + gates2 (tid<384; butterfly leaves full sums in all kc lanes) ----
    if (mv2){
      float x[12];
      #pragma unroll
      for (int i=0;i<12;i++) x[i] = shp[kc*12 + i];
      float y0=0.f,y1=0.f,y2=0.f;
      #pragma unroll
      for (int i=0;i<12;i++){
        y0 += x[i]*rwhh[0][i]; y1 += x[i]*rwhh[1][i]; y2 += x[i]*rwhh[2][i];
      }
      #pragma unroll
      for (int m=1;m<16;m<<=1){
        y0 += __shfl_xor(y0,m); y1 += __shfl_xor(y1,m); y2 += __shfl_xor(y2,m);
      }
      float dginv = sDG[t], tf1 = sTF1[t], tf2 = sTF2[t];
      int c0g = 0*H_ + slice*SH_ + h2;
      int c1g = 1*H_ + slice*SH_ + h2;
      int c2g = 2*H_ + slice*SH_ + h2;
      float a20 = (sPS[t*SC_ + 0*SH_ + h2] + tf1*sdq[par][c0g] + tf2*sdq[(t-1)&1][c0g])*dginv + sbih[c0g];
      float a21 = (sPS[t*SC_ + 1*SH_ + h2] + tf1*sdq[par][c1g] + tf2*sdq[(t-1)&1][c1g])*dginv + sbih[c1g];
      float a22 = (sPS[t*SC_ + 2*SH_ + h2] + tf1*sdq[par][c2g] + tf2*sdq[(t-1)&1][c2g])*dginv + sbih[c2g];
      float r2 = sigm_(a20 + y0 + sbhh[c0g]);
      float u2 = sigm_(a21 + y1 + sbhh[c1g]);
      float n2 = tanh_(a22 + r2*(y2 + sbhh[c2g]));
      float hn = (1.0f-u2)*n2 + u2*shp[slice*SH_ + h2];
      if (kc == 0){
        sh_new[h2] = hn;
        wsf[SL2_OFF + (unsigned)(b*N_+t)*192u + slice*SH_ + h2] = hn;
      }
    }
    __syncthreads();   // B3
    // ---- phase D: publish next delta partial — ONE u64 atomic add, fire-and-forget ----
    if (t < N_-1){
      float pc = 0.f;
      #pragma unroll
      for (int i=0;i<SH_;i++) pc += sh_new[i]*rwih[i];
      __hip_atomic_fetch_add(&ws64[D64 + ((size_t)(((t+1)&1)*4 + b))*H3_ + tid], encd_(pc),
                             __ATOMIC_RELAXED, __HIP_MEMORY_SCOPE_AGENT);
    }
  }
}

// ---------- pass 2a: tiled (8 rows/block): G^T, C, NF ----------
__global__ void __launch_bounds__(192) k_p2a(const float* __restrict__ W1,
    const float* __restrict__ Wf, const float* __restrict__ bf, float* ws, float* out)
{
  int j0 = blockIdx.x * 8, b = blockIdx.y, tid = threadIdx.x;
  __shared__ float srow[8][H_], hrow[8][H_];
  __shared__ float nfp[3][8][F_];
  for (int r=0;r<8;r++){
    srow[r][tid] = ws[SL2_OFF + (unsigned)(b*N_+j0+r)*192u + tid];
    hrow[r][tid] = ws[HL2_OFF + (unsigned)(b*N_+j0+r)*192u + tid];  // row0 garbage, C[0] unused
  }
  __syncthreads();
  float accG[8], accC[8];
  #pragma unroll
  for (int r=0;r<8;r++){ accG[r]=0.f; accC[r]=0.f; }
  for (int k=0;k<H_;k++){
    float w1a = W1[(size_t)k*H_ + tid];
    float w1b = W1[(size_t)(H_+k)*H_ + tid];
    #pragma unroll
    for (int r=0;r<8;r++){
      accG[r] += srow[r][k]*w1b;
      accC[r] += hrow[r][k]*w1a;
    }
  }
  float zc = ws[ZC_OFF + b*H_ + tid];
  #pragma unroll
  for (int r=0;r<8;r++){
    ws[G_OFF + ((size_t)b*H_ + tid)*N_ + j0 + r] = accG[r];
    ws[C_OFF + (size_t)(b*N_+j0+r)*H_ + tid] = accC[r] + zc;
  }
  int f = tid & 63, kp = tid >> 6;
  float acc[8];
  #pragma unroll
  for (int r=0;r<8;r++) acc[r] = 0.f;
  for (int i=0;i<64;i++){
    int k = kp*64 + i;
    float wfv = Wf[(size_t)k*F_ + f];
    #pragma unroll
    for (int r=0;r<8;r++) acc[r] += srow[r][k]*wfv;
  }
  #pragma unroll
  for (int r=0;r<8;r++) nfp[kp][r][f] = acc[r];
  __syncthreads();
  if (tid < F_){
    #pragma unroll
    for (int r=0;r<8;r++)
      out[NF_OUT + (size_t)(b*N_+j0+r)*F_ + tid] = nfp[0][r][tid]+nfp[1][r][tid]+nfp[2][r][tid] + bf[tid];
  }
}

// ---------- pass 2b: log-likelihood, lane-per-candidate-parent ----------
__global__ void __launch_bounds__(256) k_p2b(const float* __restrict__ W2,
    const float* __restrict__ b2p, float* ws, float* out)
{
  int t = blockIdx.x + 1, b = blockIdx.y;
  int tid = threadIdx.x; int lane = tid & 63; int wv = tid >> 6;
  __shared__ float cv[H_], w2s[H_];
  __shared__ float wsum[4];
  unsigned long long* ws64 = (unsigned long long*)ws;
  if (tid < H_){
    cv[tid] = ws[C_OFF + (size_t)(b*N_+t)*H_ + tid];
    w2s[tid] = W2[tid];
  }
  __syncthreads();
  float acc = 0.f;
  if (tid < t){
    const float* GT = ws + G_OFF + (size_t)b*H_*N_;
    float a = 0.f;
    for (int k=0;k<H_;k++) a += fmaxf(cv[k] + GT[(size_t)k*N_ + tid], 0.f) * w2s[k];
    float logit = a + b2p[0];
    float pp = 1.0f/(1.0f+__expf(-logit));
    unsigned long long an = ws64[AN64 + (size_t)(b*N_+t)*4 + (tid>>6)];
    unsigned long long tg = ws64[TG64 + (size_t)(b*N_+t)*4 + (tid>>6)];
    float anc = (float)((an >> (tid&63)) & 1ULL);
    pp = pp * (1.0f - anc);
    pp = fminf(fmaxf(pp, 1e-6f), 1.0f - 1e-6f);
    int tgb = (int)((tg >> (tid&63)) & 1ULL);
    acc = tgb ? logf(pp) : log1pf(-pp);
  }
  #pragma unroll
  for (int m=32;m>=1;m>>=1) acc += __shfl_xor(acc, m);
  if (lane == 0) wsum[wv] = acc;
  __syncthreads();
  if (tid == 0) atomicAdd(out + LL_OUT, wsum[0]+wsum[1]+wsum[2]+wsum[3]);
}

extern "C" void kernel_launch(void* const* d_in, const int* in_sizes, int n_in,
                              void* d_out, int out_size, void* d_ws, size_t ws_size,
                              hipStream_t stream) {
  (void)in_sizes; (void)n_in; (void)out_size; (void)ws_size;
  const float* z     = (const float*)d_in[0];
  const float* tgt   = (const float*)d_in[1];
  const float* Winit = (const float*)d_in[2];
  const float* binit = (const float*)d_in[3];
  const float* Wih   = (const float*)d_in[4];
  const float* Whh   = (const float*)d_in[5];
  const float* bih   = (const float*)d_in[6];
  const float* bhh   = (const float*)d_in[7];
  const float* W1    = (const float*)d_in[8];
  const float* b1    = (const float*)d_in[9];
  const float* W2    = (const float*)d_in[10];
  const float* b2    = (const float*)d_in[11];
  const float* Wf    = (const float*)d_in[12];
  const float* bf    = (const float*)d_in[13];
  float* out = (float*)d_out;
  float* ws  = (float*)d_ws;

  hipMemcpyAsync(d_out, d_in[1], (size_t)B_*N_*N_*sizeof(float), hipMemcpyDeviceToDevice, stream);

  k_pre0<<<dim3(B_), dim3(H3_), 0, stream>>>(z, Whh, bhh, ws);
  k_pre1<<<dim3(N_+1, B_), dim3(192), 0, stream>>>(z, Winit, binit, W1, b1, tgt, ws, out);
  k_pre2<<<dim3(N_, B_), dim3(64), 0, stream>>>(ws);
  k_pass1<<<dim3(64), dim3(H3_), 0, stream>>>(z, Wih, Whh, bih, bhh, ws);
  k_p2a<<<dim3(N_/8, B_), dim3(192), 0, stream>>>(W1, Wf, bf, ws, out);
  k_p2b<<<dim3(N_-1, B_), dim3(256), 0, stream>>>(W2, b2, ws, out);
}